// Round 18
// baseline (434.660 us; speedup 1.0000x reference)
//
#include <hip/hip_runtime.h>
#include <math.h>

#define NN 100000
#define EE 800000
#define ETOT (EE + NN)
#define CAP 128
#define NBLK2 440            // sort blocks
#define EPB 2048             // edges per sort block (440*2048 >= ETOT)
#define NBUCK 256            // histogram buckets; bucket = d>>9 (<=195)
#define NSCAN (NBUCK * NBLK2)
#define NGRP ((NN + 511) >> 9)   // 196 dst-groups of 512
// HID=64, HEADS=4, OBS=128, ACT=32

typedef __attribute__((ext_vector_type(4))) float f32x4;

// ---------------- GEMM: C[M,Nc] = A[M,K] @ B[K,Nc] (+bias, optional relu) ----------------
// A loads are non-temporal: every call site reads each A row exactly once (gy=1),
// so keeping A out of L2/L3 preserves residency for gather-heavy kernels.
__global__ __launch_bounds__(256) void gemm_kernel(
    const float* __restrict__ A, const float* __restrict__ B,
    const float* __restrict__ bias, float* __restrict__ C,
    int M, int K, int Nc, int doRelu)
{
    __shared__ __align__(16) float sA[16 * 68];  // [k][row 0..63]
    __shared__ __align__(16) float sB[16 * 68];  // [k][col 0..63]

    const int bm = blockIdx.x * 64;
    const int tid = threadIdx.x;
    const int ty = tid >> 4;
    const int tx = tid & 15;

    float acc[4][4] = {};

    for (int k0 = 0; k0 < K; k0 += 16) {
        {
            int r  = tid >> 2;
            int c4 = tid & 3;
            int gr = bm + r;
            f32x4 v = {0.f, 0.f, 0.f, 0.f};
            if (gr < M) v = __builtin_nontemporal_load((const f32x4*)&A[(size_t)gr * K + k0 + c4 * 4]);
            sA[(c4 * 4 + 0) * 68 + r] = v.x;
            sA[(c4 * 4 + 1) * 68 + r] = v.y;
            sA[(c4 * 4 + 2) * 68 + r] = v.z;
            sA[(c4 * 4 + 3) * 68 + r] = v.w;
        }
        {
            int row = tid >> 4;
            int c4  = (tid & 15) * 4;
            float4 v = {0.f, 0.f, 0.f, 0.f};
            if (c4 < Nc) v = *(const float4*)&B[(size_t)(k0 + row) * Nc + c4];
            *(float4*)&sB[row * 68 + c4] = v;
        }
        __syncthreads();
#pragma unroll
        for (int k = 0; k < 16; ++k) {
            float4 a0 = *(const float4*)&sA[k * 68 + ty * 4];
            float4 b0 = *(const float4*)&sB[k * 68 + tx * 4];
            float a[4] = {a0.x, a0.y, a0.z, a0.w};
            float b[4] = {b0.x, b0.y, b0.z, b0.w};
#pragma unroll
            for (int i = 0; i < 4; ++i)
#pragma unroll
                for (int j = 0; j < 4; ++j)
                    acc[i][j] = fmaf(a[i], b[j], acc[i][j]);
        }
        __syncthreads();
    }

    const int gc = tx * 4;
    float bv[4] = {0.f, 0.f, 0.f, 0.f};
    if (bias && gc < Nc) {
        bv[0] = bias[gc + 0]; bv[1] = bias[gc + 1];
        bv[2] = bias[gc + 2]; bv[3] = bias[gc + 3];
    }
    if (gc < Nc) {
#pragma unroll
        for (int i = 0; i < 4; ++i) {
            int gr = bm + ty * 4 + i;
            if (gr >= M) continue;
            float4 v;
            v.x = acc[i][0] + bv[0];
            v.y = acc[i][1] + bv[1];
            v.z = acc[i][2] + bv[2];
            v.w = acc[i][3] + bv[3];
            if (doRelu) {
                v.x = fmaxf(v.x, 0.f); v.y = fmaxf(v.y, 0.f);
                v.z = fmaxf(v.z, 0.f); v.w = fmaxf(v.w, 0.f);
            }
            *(float4*)&C[(size_t)gr * Nc + gc] = v;
        }
    }
}

__device__ __forceinline__ float lrelu(float x) { return fmaxf(x, 0.2f * x); }
__device__ __forceinline__ float fexp(float x) { return __expf(x); }  // v_exp_f32 path
__device__ __forceinline__ int edge_src(const int* ei, int e) { return e < EE ? ei[e] : e - EE; }
__device__ __forceinline__ int edge_dst(const int* ei, int e) { return e < EE ? ei[EE + e] : e - EE; }

// ================= generic 3-kernel exclusive scan (n <= 131072) =================
__global__ __launch_bounds__(256) void gscan_partial(const int* __restrict__ in, int* __restrict__ partial, int n)
{
    __shared__ int s[256];
    int b = blockIdx.x;
    int gi = b * 512 + threadIdx.x;
    int v = 0;
    if (gi < n) v += in[gi];
    if (gi + 256 < n) v += in[gi + 256];
    s[threadIdx.x] = v;
    __syncthreads();
    for (int off = 128; off > 0; off >>= 1) {
        if (threadIdx.x < off) s[threadIdx.x] += s[threadIdx.x + off];
        __syncthreads();
    }
    if (threadIdx.x == 0) partial[b] = s[0];
}

__global__ __launch_bounds__(256) void gscan_top(int* __restrict__ partial, int nb)
{
    __shared__ int s[256];
    int tid = threadIdx.x;
    s[tid] = (tid < nb) ? partial[tid] : 0;
    __syncthreads();
    for (int off = 1; off < 256; off <<= 1) {
        int t = (tid >= off) ? s[tid - off] : 0;
        __syncthreads();
        s[tid] += t;
        __syncthreads();
    }
    if (tid < nb) partial[tid] = (tid == 0) ? 0 : s[tid - 1];
}

__global__ __launch_bounds__(256) void gscan_final(
    const int* __restrict__ in, const int* __restrict__ partial, int* __restrict__ out, int n)
{
    __shared__ int s[512];
    int b = blockIdx.x;
    int tid = threadIdx.x;
    int g0 = b * 512 + tid, g1 = b * 512 + tid + 256;
    s[tid]       = (g0 < n) ? in[g0] : 0;
    s[tid + 256] = (g1 < n) ? in[g1] : 0;
    __syncthreads();
#pragma unroll
    for (int d = 0; d < 9; ++d) {
        int stride = 1 << d, nn2 = 256 >> d;
        if (tid < nn2) s[(2 * tid + 2) * stride - 1] += s[(2 * tid + 1) * stride - 1];
        __syncthreads();
    }
    if (tid == 0) s[511] = 0;
    __syncthreads();
#pragma unroll
    for (int d = 8; d >= 0; --d) {
        int stride = 1 << d, nn2 = 256 >> d;
        if (tid < nn2) {
            int i1 = (2 * tid + 1) * stride - 1, i2 = (2 * tid + 2) * stride - 1;
            int t = s[i1];
            s[i1] = s[i2];
            s[i2] += t;
        }
        __syncthreads();
    }
    int off = partial[b];
    if (g0 < n) out[g0] = s[tid] + off;
    if (g1 < n) out[g1] = s[tid + 256] + off;
}

__global__ void set_tail(int* __restrict__ row_ptr)
{
    row_ptr[NN] = ETOT;
}

// ================= counting sort of edges by dst-group =================
__global__ __launch_bounds__(256) void sort_hist(
    const int* __restrict__ ei, int* __restrict__ hist_bm, int* __restrict__ cnt)
{
    __shared__ int h[NBUCK];
    int tid = threadIdx.x, blk = blockIdx.x;
    h[tid] = 0;
    __syncthreads();
#pragma unroll
    for (int it = 0; it < EPB / 256; ++it) {
        int e = blk * EPB + it * 256 + tid;
        if (e < ETOT) {
            int d = edge_dst(ei, e);
            atomicAdd(&h[d >> 9], 1);
            atomicAdd(&cnt[d], 1);
        }
    }
    __syncthreads();
    hist_bm[tid * NBLK2 + blk] = h[tid];
}

__global__ __launch_bounds__(256) void sort_scatter(
    const int* __restrict__ ei, const int* __restrict__ off_bm, int2* __restrict__ srec)
{
    __shared__ int cur[NBUCK];
    int tid = threadIdx.x, blk = blockIdx.x;
    cur[tid] = off_bm[tid * NBLK2 + blk];
    __syncthreads();
#pragma unroll
    for (int it = 0; it < EPB / 256; ++it) {
        int e = blk * EPB + it * 256 + tid;
        if (e < ETOT) {
            int d = edge_dst(ei, e);
            int s = edge_src(ei, e);
            int pos = atomicAdd(&cur[d >> 9], 1);
            srec[pos] = make_int2(s, d);
        }
    }
}

__global__ __launch_bounds__(256) void csr_fill2(
    const int* __restrict__ row_ptr, const int2* __restrict__ srec, int* __restrict__ col_src)
{
    __shared__ int cur[512];
    int g = blockIdx.x, tid = threadIdx.x;
    int n0 = g << 9;
    for (int i = tid; i < 512; i += 256) {
        int nd = n0 + i;
        cur[i] = (nd < NN) ? row_ptr[nd] : 0;
    }
    __syncthreads();
    int lo = row_ptr[n0];
    int hi = (n0 + 512 <= NN) ? row_ptr[n0 + 512] : ETOT;
    for (int idx = lo + tid; idx < hi; idx += 256) {
        int2 r = srec[idx];
        int pos = atomicAdd(&cur[r.y - n0], 1);
        col_src[pos] = r.x;
    }
}

// ================= per-layer weight precomputes (att_vec + permW fused) =================
// blocks 0..63: B2[(h*64+k)*64+j] = W[k*256+h*64+j]; block 64: vs/vd reductions.
__global__ __launch_bounds__(256) void prep_kernel(
    const float* __restrict__ W, const float* __restrict__ attS,
    const float* __restrict__ attD, float* __restrict__ vs, float* __restrict__ vd,
    float* __restrict__ B2)
{
    int tid = threadIdx.x;
    if (blockIdx.x == 64) {
        int k = tid >> 2, h = tid & 3;
        const float* wr = W + (size_t)k * 256 + h * 64;
        const float* as = attS + h * 64;
        const float* ad = attD + h * 64;
        float ss = 0.f, sd = 0.f;
#pragma unroll
        for (int j = 0; j < 64; ++j) {
            float wv = wr[j];
            ss += wv * as[j];
            sd += wv * ad[j];
        }
        vs[tid] = ss;
        vd[tid] = sd;
    } else {
        int i = blockIdx.x * 256 + tid;   // i = r*64+j, r = h*64+k
        int r = i >> 6, j = i & 63;
        int h = r >> 6, k = r & 63;
        B2[i] = W[(size_t)k * 256 + h * 64 + j];
    }
}

// ================= attention scores directly from x =================
__global__ __launch_bounds__(256) void scores_x_kernel(
    const float* __restrict__ x, const float* __restrict__ vs,
    const float* __restrict__ vd, float4* __restrict__ a4s, float4* __restrict__ a4d)
{
    __shared__ float4 svs[64], svd[64];
    int tid = threadIdx.x;
    if (tid < 64) {
        svs[tid] = ((const float4*)vs)[tid];
        svd[tid] = ((const float4*)vd)[tid];
    }
    __syncthreads();
    int n = blockIdx.x * 256 + tid;
    if (n >= NN) return;
    const float4* xp = (const float4*)(x + (size_t)n * 64);
    float4 as = {0.f, 0.f, 0.f, 0.f}, ad = {0.f, 0.f, 0.f, 0.f};
#pragma unroll
    for (int i = 0; i < 16; ++i) {
        float4 xv = xp[i];
        float4 s0 = svs[i * 4 + 0], s1 = svs[i * 4 + 1], s2 = svs[i * 4 + 2], s3 = svs[i * 4 + 3];
        float4 d0 = svd[i * 4 + 0], d1 = svd[i * 4 + 1], d2 = svd[i * 4 + 2], d3 = svd[i * 4 + 3];
        as.x += xv.x * s0.x + xv.y * s1.x + xv.z * s2.x + xv.w * s3.x;
        as.y += xv.x * s0.y + xv.y * s1.y + xv.z * s2.y + xv.w * s3.y;
        as.z += xv.x * s0.z + xv.y * s1.z + xv.z * s2.z + xv.w * s3.z;
        as.w += xv.x * s0.w + xv.y * s1.w + xv.z * s2.w + xv.w * s3.w;
        ad.x += xv.x * d0.x + xv.y * d1.x + xv.z * d2.x + xv.w * d3.x;
        ad.y += xv.x * d0.y + xv.y * d1.y + xv.z * d2.y + xv.w * d3.y;
        ad.z += xv.x * d0.z + xv.y * d1.z + xv.z * d2.z + xv.w * d3.z;
        ad.w += xv.x * d0.w + xv.y * d1.w + xv.z * d2.w + xv.w * d3.w;
    }
    a4s[n] = as;
    a4d[n] = ad;
}

// ================= fused softmax + gather aggregation (wave per dst) =================
// R17: agg stores are non-temporal — the 100MB agg stream was evicting x (25.6MB,
// ~9x reuse) from L2/L3, causing ~100MB/dispatch of re-fetch (FETCH 137MB vs 33MB
// working set). Phase B stays scalar 4-deep (R16: 4 line streams beats wider loads).
__global__ __launch_bounds__(256) void gat_fused(
    const int* __restrict__ row_ptr, const int* __restrict__ col_src,
    const float4* __restrict__ a4s, const float4* __restrict__ a4d,
    const float* __restrict__ x, float* __restrict__ agg)
{
    __shared__ float4 sp[4][CAP];
    __shared__ int    ssrc[4][CAP];
    const int wslot = threadIdx.x >> 6;
    const int lane = threadIdx.x & 63;
    const int d = (blockIdx.x * 256 + threadIdx.x) >> 6;   // grid sized so d < NN always

    const int rs = row_ptr[d];
    const int deg = row_ptr[d + 1] - rs;
    const float4 ad = a4d[d];

    // ---- Phase A: edge-parallel p + head sums ----
    float px = 0.f, py = 0.f, pz = 0.f, pw = 0.f;
    for (int base = 0; base < deg; base += 64) {
        int idx = base + lane;
        float4 p = {0.f, 0.f, 0.f, 0.f};
        int s = 0;
        if (idx < deg) {
            s = col_src[rs + idx];
            float4 v = a4s[s];
            p.x = fexp(lrelu(v.x + ad.x));
            p.y = fexp(lrelu(v.y + ad.y));
            p.z = fexp(lrelu(v.z + ad.z));
            p.w = fexp(lrelu(v.w + ad.w));
        }
        if (idx < CAP) { sp[wslot][idx] = p; ssrc[wslot][idx] = s; }
        px += p.x; py += p.y; pz += p.z; pw += p.w;
    }
#pragma unroll
    for (int off = 32; off > 0; off >>= 1) {
        px += __shfl_xor(px, off, 64);
        py += __shfl_xor(py, off, 64);
        pz += __shfl_xor(pz, off, 64);
        pw += __shfl_xor(pw, off, 64);
    }
    const float ivx = 0.25f * __builtin_amdgcn_rcpf(px);
    const float ivy = 0.25f * __builtin_amdgcn_rcpf(py);
    const float ivz = 0.25f * __builtin_amdgcn_rcpf(pz);
    const float ivw = 0.25f * __builtin_amdgcn_rcpf(pw);

    // ---- Phase B: feature-parallel x gather (scalar, 4-deep) ----
    float a0 = 0.f, a1 = 0.f, a2 = 0.f, a3 = 0.f;
    const int lim = deg < CAP ? deg : CAP;
    int e = 0;
    for (; e + 4 <= lim; e += 4) {
        float4 p0 = sp[wslot][e + 0], p1 = sp[wslot][e + 1];
        float4 p2 = sp[wslot][e + 2], p3 = sp[wslot][e + 3];
        int s0 = ssrc[wslot][e + 0], s1 = ssrc[wslot][e + 1];
        int s2 = ssrc[wslot][e + 2], s3 = ssrc[wslot][e + 3];
        float x0 = x[(size_t)s0 * 64 + lane];
        float x1 = x[(size_t)s1 * 64 + lane];
        float x2 = x[(size_t)s2 * 64 + lane];
        float x3 = x[(size_t)s3 * 64 + lane];
        a0 += p0.x * x0 + p1.x * x1 + p2.x * x2 + p3.x * x3;
        a1 += p0.y * x0 + p1.y * x1 + p2.y * x2 + p3.y * x3;
        a2 += p0.z * x0 + p1.z * x1 + p2.z * x2 + p3.z * x3;
        a3 += p0.w * x0 + p1.w * x1 + p2.w * x2 + p3.w * x3;
    }
    for (; e < lim; ++e) {
        float4 p = sp[wslot][e];
        int s = ssrc[wslot][e];
        float xv = x[(size_t)s * 64 + lane];
        a0 = fmaf(p.x, xv, a0);
        a1 = fmaf(p.y, xv, a1);
        a2 = fmaf(p.z, xv, a2);
        a3 = fmaf(p.w, xv, a3);
    }
    for (; e < deg; ++e) {   // slow path, statistically never taken
        int s = col_src[rs + e];
        float4 v = a4s[s];
        float4 p;
        p.x = fexp(lrelu(v.x + ad.x)); p.y = fexp(lrelu(v.y + ad.y));
        p.z = fexp(lrelu(v.z + ad.z)); p.w = fexp(lrelu(v.w + ad.w));
        float xv = x[(size_t)s * 64 + lane];
        a0 = fmaf(p.x, xv, a0);
        a1 = fmaf(p.y, xv, a1);
        a2 = fmaf(p.z, xv, a2);
        a3 = fmaf(p.w, xv, a3);
    }

    float* op = agg + (size_t)d * 256;
    __builtin_nontemporal_store(a0 * ivx, &op[lane]);
    __builtin_nontemporal_store(a1 * ivy, &op[64 + lane]);
    __builtin_nontemporal_store(a2 * ivz, &op[128 + lane]);
    __builtin_nontemporal_store(a3 * ivw, &op[192 + lane]);
}

// ---------------- host-side GAT layer ----------------
static void gat_layer(float* x /* in/out [N,64] */, const float* W, const float* attS,
                      const float* attD, const float* b, const int* row_ptr, const int* col_src,
                      float* agg, float4* a4s, float4* a4d,
                      float* vs, float* vd, float* B2, hipStream_t stream)
{
    prep_kernel<<<65, 256, 0, stream>>>(W, attS, attD, vs, vd, B2);
    scores_x_kernel<<<(NN + 255) / 256, 256, 0, stream>>>(x, vs, vd, a4s, a4d);
    gat_fused<<<(NN * 64) / 256, 256, 0, stream>>>(row_ptr, col_src, a4s, a4d, x, agg);
    // x_out = relu(agg @ B2 + b)   (0.25 folded into iv)
    gemm_kernel<<<(NN + 63) / 64, 256, 0, stream>>>(agg, B2, b, x, NN, 256, 64, 1);
}

extern "C" void kernel_launch(void* const* d_in, const int* in_sizes, int n_in,
                              void* d_out, int out_size, void* d_ws, size_t ws_size,
                              hipStream_t stream)
{
    const float* obs     = (const float*)d_in[0];
    const int*   ei      = (const int*)d_in[1];
    const float* enc_w1  = (const float*)d_in[2];
    const float* enc_b1  = (const float*)d_in[3];
    const float* enc_w2  = (const float*)d_in[4];
    const float* enc_b2  = (const float*)d_in[5];
    const float* gat1_w  = (const float*)d_in[6];
    const float* gat1_as = (const float*)d_in[7];
    const float* gat1_ad = (const float*)d_in[8];
    const float* gat1_b  = (const float*)d_in[9];
    const float* gat2_w  = (const float*)d_in[10];
    const float* gat2_as = (const float*)d_in[11];
    const float* gat2_ad = (const float*)d_in[12];
    const float* gat2_b  = (const float*)d_in[13];
    const float* dec_w1  = (const float*)d_in[14];
    const float* dec_b1  = (const float*)d_in[15];
    const float* dec_w2  = (const float*)d_in[16];
    const float* dec_b2  = (const float*)d_in[17];

    float* ws = (float*)d_ws;
    float* bufA    = ws;                                   // [N,64]
    float* bufB    = bufA + (size_t)NN * 64;               // [N,64]  (x)
    float* agg     = bufB + (size_t)NN * 64;               // [N,256]
    float4* a4s    = (float4*)(agg + (size_t)NN * 256);    // [N]
    float4* a4d    = a4s + NN;                             // [N]
    int* row_ptr   = (int*)(a4d + NN);                     // [N+1] (+pad)
    int* cnt       = row_ptr + NN + 4;                     // [N]
    int* col_src   = cnt + NN;                             // [ETOT]
    int* partial   = col_src + ETOT;                       // [256]
    int* partial2  = partial + 256;                        // [256]
    float* vs      = (float*)(partial2 + 256);             // [256]
    float* vd      = vs + 256;                             // [256]
    float* B2      = vd + 256;                             // [256*64]
    int* hist      = (int*)(B2 + 256 * 64);                // [NSCAN]
    int* off_bm    = hist + NSCAN;                         // [NSCAN]
    int2* srec     = (int2*)(off_bm + NSCAN);              // [ETOT]

    const int GB = (NN + 63) / 64;
    const int NCHUNK_N = (NN + 511) / 512;        // 196
    const int NCHUNK_S = (NSCAN + 511) / 512;     // 220

    // ---- CSR build via counting sort (once, reused by both GAT layers) ----
    hipMemsetAsync(cnt, 0, (size_t)NN * sizeof(int), stream);
    sort_hist<<<NBLK2, 256, 0, stream>>>(ei, hist, cnt);
    gscan_partial<<<NCHUNK_N, 256, 0, stream>>>(cnt, partial, NN);
    gscan_top<<<1, 256, 0, stream>>>(partial, NCHUNK_N);
    gscan_final<<<NCHUNK_N, 256, 0, stream>>>(cnt, partial, row_ptr, NN);
    set_tail<<<1, 1, 0, stream>>>(row_ptr);
    gscan_partial<<<NCHUNK_S, 256, 0, stream>>>(hist, partial2, NSCAN);
    gscan_top<<<1, 256, 0, stream>>>(partial2, NCHUNK_S);
    gscan_final<<<NCHUNK_S, 256, 0, stream>>>(hist, partial2, off_bm, NSCAN);
    sort_scatter<<<NBLK2, 256, 0, stream>>>(ei, off_bm, srec);
    csr_fill2<<<NGRP, 256, 0, stream>>>(row_ptr, srec, col_src);

    // ---- encoder ----
    gemm_kernel<<<GB, 256, 0, stream>>>(obs, enc_w1, enc_b1, bufA, NN, 128, 64, 1);
    gemm_kernel<<<GB, 256, 0, stream>>>(bufA, enc_w2, enc_b2, bufB, NN, 64, 64, 0);

    // ---- GAT layers (x lives in bufB) ----
    gat_layer(bufB, gat1_w, gat1_as, gat1_ad, gat1_b, row_ptr, col_src, agg, a4s, a4d, vs, vd, B2, stream);
    gat_layer(bufB, gat2_w, gat2_as, gat2_ad, gat2_b, row_ptr, col_src, agg, a4s, a4d, vs, vd, B2, stream);

    // ---- decoder ----
    gemm_kernel<<<GB, 256, 0, stream>>>(bufB, dec_w1, dec_b1, bufA, NN, 64, 64, 1);
    gemm_kernel<<<GB, 256, 0, stream>>>(bufA, dec_w2, dec_b2, (float*)d_out, NN, 64, 32, 0);
}

// Round 19
// 419.337 us; speedup vs baseline: 1.0365x; 1.0365x over previous
//
#include <hip/hip_runtime.h>
#include <math.h>

#define NN 100000
#define EE 800000
#define ETOT (EE + NN)
#define CAP 128
#define NBLK2 440            // sort blocks
#define EPB 2048             // edges per sort block (440*2048 >= ETOT)
#define NBUCK 256            // histogram buckets; bucket = d>>9 (<=195)
#define NSCAN (NBUCK * NBLK2)
#define NGRP ((NN + 511) >> 9)   // 196 dst-groups of 512
// HID=64, HEADS=4, OBS=128, ACT=32

// ---------------- GEMM: C[M,Nc] = A[M,K] @ B[K,Nc] (+bias, optional relu) ----------------
// R18: A loads reverted to normal cached float4 (R17's NT loads bypassed L2/L3 and
// cost +21us/dispatch at 42% occupancy; agg reads need the cache path).
__global__ __launch_bounds__(256) void gemm_kernel(
    const float* __restrict__ A, const float* __restrict__ B,
    const float* __restrict__ bias, float* __restrict__ C,
    int M, int K, int Nc, int doRelu)
{
    __shared__ __align__(16) float sA[16 * 68];  // [k][row 0..63]
    __shared__ __align__(16) float sB[16 * 68];  // [k][col 0..63]

    const int bm = blockIdx.x * 64;
    const int tid = threadIdx.x;
    const int ty = tid >> 4;
    const int tx = tid & 15;

    float acc[4][4] = {};

    for (int k0 = 0; k0 < K; k0 += 16) {
        {
            int r  = tid >> 2;
            int c4 = tid & 3;
            int gr = bm + r;
            float4 v = {0.f, 0.f, 0.f, 0.f};
            if (gr < M) v = *(const float4*)&A[(size_t)gr * K + k0 + c4 * 4];
            sA[(c4 * 4 + 0) * 68 + r] = v.x;
            sA[(c4 * 4 + 1) * 68 + r] = v.y;
            sA[(c4 * 4 + 2) * 68 + r] = v.z;
            sA[(c4 * 4 + 3) * 68 + r] = v.w;
        }
        {
            int row = tid >> 4;
            int c4  = (tid & 15) * 4;
            float4 v = {0.f, 0.f, 0.f, 0.f};
            if (c4 < Nc) v = *(const float4*)&B[(size_t)(k0 + row) * Nc + c4];
            *(float4*)&sB[row * 68 + c4] = v;
        }
        __syncthreads();
#pragma unroll
        for (int k = 0; k < 16; ++k) {
            float4 a0 = *(const float4*)&sA[k * 68 + ty * 4];
            float4 b0 = *(const float4*)&sB[k * 68 + tx * 4];
            float a[4] = {a0.x, a0.y, a0.z, a0.w};
            float b[4] = {b0.x, b0.y, b0.z, b0.w};
#pragma unroll
            for (int i = 0; i < 4; ++i)
#pragma unroll
                for (int j = 0; j < 4; ++j)
                    acc[i][j] = fmaf(a[i], b[j], acc[i][j]);
        }
        __syncthreads();
    }

    const int gc = tx * 4;
    float bv[4] = {0.f, 0.f, 0.f, 0.f};
    if (bias && gc < Nc) {
        bv[0] = bias[gc + 0]; bv[1] = bias[gc + 1];
        bv[2] = bias[gc + 2]; bv[3] = bias[gc + 3];
    }
    if (gc < Nc) {
#pragma unroll
        for (int i = 0; i < 4; ++i) {
            int gr = bm + ty * 4 + i;
            if (gr >= M) continue;
            float4 v;
            v.x = acc[i][0] + bv[0];
            v.y = acc[i][1] + bv[1];
            v.z = acc[i][2] + bv[2];
            v.w = acc[i][3] + bv[3];
            if (doRelu) {
                v.x = fmaxf(v.x, 0.f); v.y = fmaxf(v.y, 0.f);
                v.z = fmaxf(v.z, 0.f); v.w = fmaxf(v.w, 0.f);
            }
            *(float4*)&C[(size_t)gr * Nc + gc] = v;
        }
    }
}

__device__ __forceinline__ float lrelu(float x) { return fmaxf(x, 0.2f * x); }
__device__ __forceinline__ float fexp(float x) { return __expf(x); }  // v_exp_f32 path
__device__ __forceinline__ int edge_src(const int* ei, int e) { return e < EE ? ei[e] : e - EE; }
__device__ __forceinline__ int edge_dst(const int* ei, int e) { return e < EE ? ei[EE + e] : e - EE; }

// ================= generic 3-kernel exclusive scan (n <= 131072) =================
__global__ __launch_bounds__(256) void gscan_partial(const int* __restrict__ in, int* __restrict__ partial, int n)
{
    __shared__ int s[256];
    int b = blockIdx.x;
    int gi = b * 512 + threadIdx.x;
    int v = 0;
    if (gi < n) v += in[gi];
    if (gi + 256 < n) v += in[gi + 256];
    s[threadIdx.x] = v;
    __syncthreads();
    for (int off = 128; off > 0; off >>= 1) {
        if (threadIdx.x < off) s[threadIdx.x] += s[threadIdx.x + off];
        __syncthreads();
    }
    if (threadIdx.x == 0) partial[b] = s[0];
}

__global__ __launch_bounds__(256) void gscan_top(int* __restrict__ partial, int nb)
{
    __shared__ int s[256];
    int tid = threadIdx.x;
    s[tid] = (tid < nb) ? partial[tid] : 0;
    __syncthreads();
    for (int off = 1; off < 256; off <<= 1) {
        int t = (tid >= off) ? s[tid - off] : 0;
        __syncthreads();
        s[tid] += t;
        __syncthreads();
    }
    if (tid < nb) partial[tid] = (tid == 0) ? 0 : s[tid - 1];
}

__global__ __launch_bounds__(256) void gscan_final(
    const int* __restrict__ in, const int* __restrict__ partial, int* __restrict__ out, int n)
{
    __shared__ int s[512];
    int b = blockIdx.x;
    int tid = threadIdx.x;
    int g0 = b * 512 + tid, g1 = b * 512 + tid + 256;
    s[tid]       = (g0 < n) ? in[g0] : 0;
    s[tid + 256] = (g1 < n) ? in[g1] : 0;
    __syncthreads();
#pragma unroll
    for (int d = 0; d < 9; ++d) {
        int stride = 1 << d, nn2 = 256 >> d;
        if (tid < nn2) s[(2 * tid + 2) * stride - 1] += s[(2 * tid + 1) * stride - 1];
        __syncthreads();
    }
    if (tid == 0) s[511] = 0;
    __syncthreads();
#pragma unroll
    for (int d = 8; d >= 0; --d) {
        int stride = 1 << d, nn2 = 256 >> d;
        if (tid < nn2) {
            int i1 = (2 * tid + 1) * stride - 1, i2 = (2 * tid + 2) * stride - 1;
            int t = s[i1];
            s[i1] = s[i2];
            s[i2] += t;
        }
        __syncthreads();
    }
    int off = partial[b];
    if (g0 < n) out[g0] = s[tid] + off;
    if (g1 < n) out[g1] = s[tid + 256] + off;
}

__global__ void set_tail(int* __restrict__ row_ptr)
{
    row_ptr[NN] = ETOT;
}

// ================= counting sort of edges by dst-group =================
__global__ __launch_bounds__(256) void sort_hist(
    const int* __restrict__ ei, int* __restrict__ hist_bm, int* __restrict__ cnt)
{
    __shared__ int h[NBUCK];
    int tid = threadIdx.x, blk = blockIdx.x;
    h[tid] = 0;
    __syncthreads();
#pragma unroll
    for (int it = 0; it < EPB / 256; ++it) {
        int e = blk * EPB + it * 256 + tid;
        if (e < ETOT) {
            int d = edge_dst(ei, e);
            atomicAdd(&h[d >> 9], 1);
            atomicAdd(&cnt[d], 1);
        }
    }
    __syncthreads();
    hist_bm[tid * NBLK2 + blk] = h[tid];
}

__global__ __launch_bounds__(256) void sort_scatter(
    const int* __restrict__ ei, const int* __restrict__ off_bm, int2* __restrict__ srec)
{
    __shared__ int cur[NBUCK];
    int tid = threadIdx.x, blk = blockIdx.x;
    cur[tid] = off_bm[tid * NBLK2 + blk];
    __syncthreads();
#pragma unroll
    for (int it = 0; it < EPB / 256; ++it) {
        int e = blk * EPB + it * 256 + tid;
        if (e < ETOT) {
            int d = edge_dst(ei, e);
            int s = edge_src(ei, e);
            int pos = atomicAdd(&cur[d >> 9], 1);
            srec[pos] = make_int2(s, d);
        }
    }
}

__global__ __launch_bounds__(256) void csr_fill2(
    const int* __restrict__ row_ptr, const int2* __restrict__ srec, int* __restrict__ col_src)
{
    __shared__ int cur[512];
    int g = blockIdx.x, tid = threadIdx.x;
    int n0 = g << 9;
    for (int i = tid; i < 512; i += 256) {
        int nd = n0 + i;
        cur[i] = (nd < NN) ? row_ptr[nd] : 0;
    }
    __syncthreads();
    int lo = row_ptr[n0];
    int hi = (n0 + 512 <= NN) ? row_ptr[n0 + 512] : ETOT;
    for (int idx = lo + tid; idx < hi; idx += 256) {
        int2 r = srec[idx];
        int pos = atomicAdd(&cur[r.y - n0], 1);
        col_src[pos] = r.x;
    }
}

// ================= per-layer weight precomputes (att_vec + permW fused) =================
__global__ __launch_bounds__(256) void prep_kernel(
    const float* __restrict__ W, const float* __restrict__ attS,
    const float* __restrict__ attD, float* __restrict__ vs, float* __restrict__ vd,
    float* __restrict__ B2)
{
    int tid = threadIdx.x;
    if (blockIdx.x == 64) {
        int k = tid >> 2, h = tid & 3;
        const float* wr = W + (size_t)k * 256 + h * 64;
        const float* as = attS + h * 64;
        const float* ad = attD + h * 64;
        float ss = 0.f, sd = 0.f;
#pragma unroll
        for (int j = 0; j < 64; ++j) {
            float wv = wr[j];
            ss += wv * as[j];
            sd += wv * ad[j];
        }
        vs[tid] = ss;
        vd[tid] = sd;
    } else {
        int i = blockIdx.x * 256 + tid;   // i = r*64+j, r = h*64+k
        int r = i >> 6, j = i & 63;
        int h = r >> 6, k = r & 63;
        B2[i] = W[(size_t)k * 256 + h * 64 + j];
    }
}

// ================= attention scores directly from x =================
__global__ __launch_bounds__(256) void scores_x_kernel(
    const float* __restrict__ x, const float* __restrict__ vs,
    const float* __restrict__ vd, float4* __restrict__ a4s, float4* __restrict__ a4d)
{
    __shared__ float4 svs[64], svd[64];
    int tid = threadIdx.x;
    if (tid < 64) {
        svs[tid] = ((const float4*)vs)[tid];
        svd[tid] = ((const float4*)vd)[tid];
    }
    __syncthreads();
    int n = blockIdx.x * 256 + tid;
    if (n >= NN) return;
    const float4* xp = (const float4*)(x + (size_t)n * 64);
    float4 as = {0.f, 0.f, 0.f, 0.f}, ad = {0.f, 0.f, 0.f, 0.f};
#pragma unroll
    for (int i = 0; i < 16; ++i) {
        float4 xv = xp[i];
        float4 s0 = svs[i * 4 + 0], s1 = svs[i * 4 + 1], s2 = svs[i * 4 + 2], s3 = svs[i * 4 + 3];
        float4 d0 = svd[i * 4 + 0], d1 = svd[i * 4 + 1], d2 = svd[i * 4 + 2], d3 = svd[i * 4 + 3];
        as.x += xv.x * s0.x + xv.y * s1.x + xv.z * s2.x + xv.w * s3.x;
        as.y += xv.x * s0.y + xv.y * s1.y + xv.z * s2.y + xv.w * s3.y;
        as.z += xv.x * s0.z + xv.y * s1.z + xv.z * s2.z + xv.w * s3.z;
        as.w += xv.x * s0.w + xv.y * s1.w + xv.z * s2.w + xv.w * s3.w;
        ad.x += xv.x * d0.x + xv.y * d1.x + xv.z * d2.x + xv.w * d3.x;
        ad.y += xv.x * d0.y + xv.y * d1.y + xv.z * d2.y + xv.w * d3.y;
        ad.z += xv.x * d0.z + xv.y * d1.z + xv.z * d2.z + xv.w * d3.z;
        ad.w += xv.x * d0.w + xv.y * d1.w + xv.z * d2.w + xv.w * d3.w;
    }
    a4s[n] = as;
    a4d[n] = ad;
}

// ================= fused softmax + gather aggregation (wave per dst) =================
// NT agg stores kept (R18 decomposition: they bought ~13us/dispatch by preserving
// x residency in L2/L3 for the gathers). Phase B scalar 4-deep (R16).
__global__ __launch_bounds__(256) void gat_fused(
    const int* __restrict__ row_ptr, const int* __restrict__ col_src,
    const float4* __restrict__ a4s, const float4* __restrict__ a4d,
    const float* __restrict__ x, float* __restrict__ agg)
{
    __shared__ float4 sp[4][CAP];
    __shared__ int    ssrc[4][CAP];
    const int wslot = threadIdx.x >> 6;
    const int lane = threadIdx.x & 63;
    const int d = (blockIdx.x * 256 + threadIdx.x) >> 6;   // grid sized so d < NN always

    const int rs = row_ptr[d];
    const int deg = row_ptr[d + 1] - rs;
    const float4 ad = a4d[d];

    // ---- Phase A: edge-parallel p + head sums ----
    float px = 0.f, py = 0.f, pz = 0.f, pw = 0.f;
    for (int base = 0; base < deg; base += 64) {
        int idx = base + lane;
        float4 p = {0.f, 0.f, 0.f, 0.f};
        int s = 0;
        if (idx < deg) {
            s = col_src[rs + idx];
            float4 v = a4s[s];
            p.x = fexp(lrelu(v.x + ad.x));
            p.y = fexp(lrelu(v.y + ad.y));
            p.z = fexp(lrelu(v.z + ad.z));
            p.w = fexp(lrelu(v.w + ad.w));
        }
        if (idx < CAP) { sp[wslot][idx] = p; ssrc[wslot][idx] = s; }
        px += p.x; py += p.y; pz += p.z; pw += p.w;
    }
#pragma unroll
    for (int off = 32; off > 0; off >>= 1) {
        px += __shfl_xor(px, off, 64);
        py += __shfl_xor(py, off, 64);
        pz += __shfl_xor(pz, off, 64);
        pw += __shfl_xor(pw, off, 64);
    }
    const float ivx = 0.25f * __builtin_amdgcn_rcpf(px);
    const float ivy = 0.25f * __builtin_amdgcn_rcpf(py);
    const float ivz = 0.25f * __builtin_amdgcn_rcpf(pz);
    const float ivw = 0.25f * __builtin_amdgcn_rcpf(pw);

    // ---- Phase B: feature-parallel x gather (scalar, 4-deep) ----
    float a0 = 0.f, a1 = 0.f, a2 = 0.f, a3 = 0.f;
    const int lim = deg < CAP ? deg : CAP;
    int e = 0;
    for (; e + 4 <= lim; e += 4) {
        float4 p0 = sp[wslot][e + 0], p1 = sp[wslot][e + 1];
        float4 p2 = sp[wslot][e + 2], p3 = sp[wslot][e + 3];
        int s0 = ssrc[wslot][e + 0], s1 = ssrc[wslot][e + 1];
        int s2 = ssrc[wslot][e + 2], s3 = ssrc[wslot][e + 3];
        float x0 = x[(size_t)s0 * 64 + lane];
        float x1 = x[(size_t)s1 * 64 + lane];
        float x2 = x[(size_t)s2 * 64 + lane];
        float x3 = x[(size_t)s3 * 64 + lane];
        a0 += p0.x * x0 + p1.x * x1 + p2.x * x2 + p3.x * x3;
        a1 += p0.y * x0 + p1.y * x1 + p2.y * x2 + p3.y * x3;
        a2 += p0.z * x0 + p1.z * x1 + p2.z * x2 + p3.z * x3;
        a3 += p0.w * x0 + p1.w * x1 + p2.w * x2 + p3.w * x3;
    }
    for (; e < lim; ++e) {
        float4 p = sp[wslot][e];
        int s = ssrc[wslot][e];
        float xv = x[(size_t)s * 64 + lane];
        a0 = fmaf(p.x, xv, a0);
        a1 = fmaf(p.y, xv, a1);
        a2 = fmaf(p.z, xv, a2);
        a3 = fmaf(p.w, xv, a3);
    }
    for (; e < deg; ++e) {   // slow path, statistically never taken
        int s = col_src[rs + e];
        float4 v = a4s[s];
        float4 p;
        p.x = fexp(lrelu(v.x + ad.x)); p.y = fexp(lrelu(v.y + ad.y));
        p.z = fexp(lrelu(v.z + ad.z)); p.w = fexp(lrelu(v.w + ad.w));
        float xv = x[(size_t)s * 64 + lane];
        a0 = fmaf(p.x, xv, a0);
        a1 = fmaf(p.y, xv, a1);
        a2 = fmaf(p.z, xv, a2);
        a3 = fmaf(p.w, xv, a3);
    }

    float* op = agg + (size_t)d * 256;
    __builtin_nontemporal_store(a0 * ivx, &op[lane]);
    __builtin_nontemporal_store(a1 * ivy, &op[64 + lane]);
    __builtin_nontemporal_store(a2 * ivz, &op[128 + lane]);
    __builtin_nontemporal_store(a3 * ivw, &op[192 + lane]);
}

// ---------------- host-side GAT layer ----------------
static void gat_layer(float* x /* in/out [N,64] */, const float* W, const float* attS,
                      const float* attD, const float* b, const int* row_ptr, const int* col_src,
                      float* agg, float4* a4s, float4* a4d,
                      float* vs, float* vd, float* B2, hipStream_t stream)
{
    prep_kernel<<<65, 256, 0, stream>>>(W, attS, attD, vs, vd, B2);
    scores_x_kernel<<<(NN + 255) / 256, 256, 0, stream>>>(x, vs, vd, a4s, a4d);
    gat_fused<<<(NN * 64) / 256, 256, 0, stream>>>(row_ptr, col_src, a4s, a4d, x, agg);
    // x_out = relu(agg @ B2 + b)   (0.25 folded into iv)
    gemm_kernel<<<(NN + 63) / 64, 256, 0, stream>>>(agg, B2, b, x, NN, 256, 64, 1);
}

extern "C" void kernel_launch(void* const* d_in, const int* in_sizes, int n_in,
                              void* d_out, int out_size, void* d_ws, size_t ws_size,
                              hipStream_t stream)
{
    const float* obs     = (const float*)d_in[0];
    const int*   ei      = (const int*)d_in[1];
    const float* enc_w1  = (const float*)d_in[2];
    const float* enc_b1  = (const float*)d_in[3];
    const float* enc_w2  = (const float*)d_in[4];
    const float* enc_b2  = (const float*)d_in[5];
    const float* gat1_w  = (const float*)d_in[6];
    const float* gat1_as = (const float*)d_in[7];
    const float* gat1_ad = (const float*)d_in[8];
    const float* gat1_b  = (const float*)d_in[9];
    const float* gat2_w  = (const float*)d_in[10];
    const float* gat2_as = (const float*)d_in[11];
    const float* gat2_ad = (const float*)d_in[12];
    const float* gat2_b  = (const float*)d_in[13];
    const float* dec_w1  = (const float*)d_in[14];
    const float* dec_b1  = (const float*)d_in[15];
    const float* dec_w2  = (const float*)d_in[16];
    const float* dec_b2  = (const float*)d_in[17];

    float* ws = (float*)d_ws;
    float* bufA    = ws;                                   // [N,64]
    float* bufB    = bufA + (size_t)NN * 64;               // [N,64]  (x)
    float* agg     = bufB + (size_t)NN * 64;               // [N,256]
    float4* a4s    = (float4*)(agg + (size_t)NN * 256);    // [N]
    float4* a4d    = a4s + NN;                             // [N]
    int* row_ptr   = (int*)(a4d + NN);                     // [N+1] (+pad)
    int* cnt       = row_ptr + NN + 4;                     // [N]
    int* col_src   = cnt + NN;                             // [ETOT]
    int* partial   = col_src + ETOT;                       // [256]
    int* partial2  = partial + 256;                        // [256]
    float* vs      = (float*)(partial2 + 256);             // [256]
    float* vd      = vs + 256;                             // [256]
    float* B2      = vd + 256;                             // [256*64]
    int* hist      = (int*)(B2 + 256 * 64);                // [NSCAN]
    int* off_bm    = hist + NSCAN;                         // [NSCAN]
    int2* srec     = (int2*)(off_bm + NSCAN);              // [ETOT]

    const int GB = (NN + 63) / 64;
    const int NCHUNK_N = (NN + 511) / 512;        // 196
    const int NCHUNK_S = (NSCAN + 511) / 512;     // 220

    // ---- CSR build via counting sort (once, reused by both GAT layers) ----
    hipMemsetAsync(cnt, 0, (size_t)NN * sizeof(int), stream);
    sort_hist<<<NBLK2, 256, 0, stream>>>(ei, hist, cnt);
    gscan_partial<<<NCHUNK_N, 256, 0, stream>>>(cnt, partial, NN);
    gscan_top<<<1, 256, 0, stream>>>(partial, NCHUNK_N);
    gscan_final<<<NCHUNK_N, 256, 0, stream>>>(cnt, partial, row_ptr, NN);
    set_tail<<<1, 1, 0, stream>>>(row_ptr);
    gscan_partial<<<NCHUNK_S, 256, 0, stream>>>(hist, partial2, NSCAN);
    gscan_top<<<1, 256, 0, stream>>>(partial2, NCHUNK_S);
    gscan_final<<<NCHUNK_S, 256, 0, stream>>>(hist, partial2, off_bm, NSCAN);
    sort_scatter<<<NBLK2, 256, 0, stream>>>(ei, off_bm, srec);
    csr_fill2<<<NGRP, 256, 0, stream>>>(row_ptr, srec, col_src);

    // ---- encoder ----
    gemm_kernel<<<GB, 256, 0, stream>>>(obs, enc_w1, enc_b1, bufA, NN, 128, 64, 1);
    gemm_kernel<<<GB, 256, 0, stream>>>(bufA, enc_w2, enc_b2, bufB, NN, 64, 64, 0);

    // ---- GAT layers (x lives in bufB) ----
    gat_layer(bufB, gat1_w, gat1_as, gat1_ad, gat1_b, row_ptr, col_src, agg, a4s, a4d, vs, vd, B2, stream);
    gat_layer(bufB, gat2_w, gat2_as, gat2_ad, gat2_b, row_ptr, col_src, agg, a4s, a4d, vs, vd, B2, stream);

    // ---- decoder ----
    gemm_kernel<<<GB, 256, 0, stream>>>(bufB, dec_w1, dec_b1, bufA, NN, 64, 64, 1);
    gemm_kernel<<<GB, 256, 0, stream>>>(bufA, dec_w2, dec_b2, (float*)d_out, NN, 64, 32, 0);
}

// Round 20
// 414.435 us; speedup vs baseline: 1.0488x; 1.0118x over previous
//
#include <hip/hip_runtime.h>
#include <math.h>

#define NN 100000
#define EE 800000
#define ETOT (EE + NN)
#define CAP 128
#define NBLK2 440            // sort blocks
#define EPB 2048             // edges per sort block (440*2048 >= ETOT)
#define NBUCK 256            // histogram buckets; bucket = d>>9 (<=195)
#define NSCAN (NBUCK * NBLK2)
#define NGRP ((NN + 511) >> 9)   // 196 dst-groups of 512
// HID=64, HEADS=4, OBS=128, ACT=32

// ---------------- GEMM: C[M,Nc] = A[M,K] @ B[K,Nc] (+bias, optional relu) ----------------
// R19: 2-phase register pipeline — issue tile t+1 global loads BEFORE computing tile t
// (stage regs: 1 float4 A + 1 float4 B per thread, +8 VGPR). The old load->LDS->barrier
// sequence exposed a full HBM round-trip per 16-K tile (VALUBusy 43%, latency-bound).
__global__ __launch_bounds__(256) void gemm_kernel(
    const float* __restrict__ A, const float* __restrict__ B,
    const float* __restrict__ bias, float* __restrict__ C,
    int M, int K, int Nc, int doRelu)
{
    __shared__ __align__(16) float sA[16 * 68];  // [k][row 0..63]
    __shared__ __align__(16) float sB[16 * 68];  // [k][col 0..63]

    const int bm = blockIdx.x * 64;
    const int tid = threadIdx.x;
    const int ty = tid >> 4;
    const int tx = tid & 15;

    const int ar  = tid >> 2;        // A stage row 0..63
    const int ac  = (tid & 3) * 4;   // A stage k-offset (float4)
    const int brw = tid >> 4;        // B stage row 0..15
    const int bc  = (tid & 15) * 4;  // B stage col (float4)
    const int grA = bm + ar;

    float acc[4][4] = {};
    float4 ra = {0.f, 0.f, 0.f, 0.f}, rb = {0.f, 0.f, 0.f, 0.f};
    const int NT = K >> 4;

    // prologue: load tile 0 into regs
    if (grA < M) ra = *(const float4*)&A[(size_t)grA * K + ac];
    if (bc < Nc) rb = *(const float4*)&B[(size_t)brw * Nc + bc];

    for (int t = 0; t < NT; ++t) {
        // write staged regs to LDS (transpose A)
        sA[(ac + 0) * 68 + ar] = ra.x;
        sA[(ac + 1) * 68 + ar] = ra.y;
        sA[(ac + 2) * 68 + ar] = ra.z;
        sA[(ac + 3) * 68 + ar] = ra.w;
        *(float4*)&sB[brw * 68 + bc] = rb;
        __syncthreads();

        // issue next-tile loads (latency hides under the 256-FMA compute below)
        if (t + 1 < NT) {
            const int k0 = (t + 1) << 4;
            ra = make_float4(0.f, 0.f, 0.f, 0.f);
            rb = make_float4(0.f, 0.f, 0.f, 0.f);
            if (grA < M) ra = *(const float4*)&A[(size_t)grA * K + k0 + ac];
            if (bc < Nc) rb = *(const float4*)&B[(size_t)(k0 + brw) * Nc + bc];
        }

#pragma unroll
        for (int k = 0; k < 16; ++k) {
            float4 a0 = *(const float4*)&sA[k * 68 + ty * 4];
            float4 b0 = *(const float4*)&sB[k * 68 + tx * 4];
            float a[4] = {a0.x, a0.y, a0.z, a0.w};
            float b[4] = {b0.x, b0.y, b0.z, b0.w};
#pragma unroll
            for (int i = 0; i < 4; ++i)
#pragma unroll
                for (int j = 0; j < 4; ++j)
                    acc[i][j] = fmaf(a[i], b[j], acc[i][j]);
        }
        __syncthreads();
    }

    const int gc = tx * 4;
    float bv[4] = {0.f, 0.f, 0.f, 0.f};
    if (bias && gc < Nc) {
        bv[0] = bias[gc + 0]; bv[1] = bias[gc + 1];
        bv[2] = bias[gc + 2]; bv[3] = bias[gc + 3];
    }
    if (gc < Nc) {
#pragma unroll
        for (int i = 0; i < 4; ++i) {
            int gr = bm + ty * 4 + i;
            if (gr >= M) continue;
            float4 v;
            v.x = acc[i][0] + bv[0];
            v.y = acc[i][1] + bv[1];
            v.z = acc[i][2] + bv[2];
            v.w = acc[i][3] + bv[3];
            if (doRelu) {
                v.x = fmaxf(v.x, 0.f); v.y = fmaxf(v.y, 0.f);
                v.z = fmaxf(v.z, 0.f); v.w = fmaxf(v.w, 0.f);
            }
            *(float4*)&C[(size_t)gr * Nc + gc] = v;
        }
    }
}

__device__ __forceinline__ float lrelu(float x) { return fmaxf(x, 0.2f * x); }
__device__ __forceinline__ float fexp(float x) { return __expf(x); }  // v_exp_f32 path
__device__ __forceinline__ int edge_src(const int* ei, int e) { return e < EE ? ei[e] : e - EE; }
__device__ __forceinline__ int edge_dst(const int* ei, int e) { return e < EE ? ei[EE + e] : e - EE; }

// ================= generic 3-kernel exclusive scan (n <= 131072) =================
__global__ __launch_bounds__(256) void gscan_partial(const int* __restrict__ in, int* __restrict__ partial, int n)
{
    __shared__ int s[256];
    int b = blockIdx.x;
    int gi = b * 512 + threadIdx.x;
    int v = 0;
    if (gi < n) v += in[gi];
    if (gi + 256 < n) v += in[gi + 256];
    s[threadIdx.x] = v;
    __syncthreads();
    for (int off = 128; off > 0; off >>= 1) {
        if (threadIdx.x < off) s[threadIdx.x] += s[threadIdx.x + off];
        __syncthreads();
    }
    if (threadIdx.x == 0) partial[b] = s[0];
}

__global__ __launch_bounds__(256) void gscan_top(int* __restrict__ partial, int nb)
{
    __shared__ int s[256];
    int tid = threadIdx.x;
    s[tid] = (tid < nb) ? partial[tid] : 0;
    __syncthreads();
    for (int off = 1; off < 256; off <<= 1) {
        int t = (tid >= off) ? s[tid - off] : 0;
        __syncthreads();
        s[tid] += t;
        __syncthreads();
    }
    if (tid < nb) partial[tid] = (tid == 0) ? 0 : s[tid - 1];
}

__global__ __launch_bounds__(256) void gscan_final(
    const int* __restrict__ in, const int* __restrict__ partial, int* __restrict__ out, int n)
{
    __shared__ int s[512];
    int b = blockIdx.x;
    int tid = threadIdx.x;
    int g0 = b * 512 + tid, g1 = b * 512 + tid + 256;
    s[tid]       = (g0 < n) ? in[g0] : 0;
    s[tid + 256] = (g1 < n) ? in[g1] : 0;
    __syncthreads();
#pragma unroll
    for (int d = 0; d < 9; ++d) {
        int stride = 1 << d, nn2 = 256 >> d;
        if (tid < nn2) s[(2 * tid + 2) * stride - 1] += s[(2 * tid + 1) * stride - 1];
        __syncthreads();
    }
    if (tid == 0) s[511] = 0;
    __syncthreads();
#pragma unroll
    for (int d = 8; d >= 0; --d) {
        int stride = 1 << d, nn2 = 256 >> d;
        if (tid < nn2) {
            int i1 = (2 * tid + 1) * stride - 1, i2 = (2 * tid + 2) * stride - 1;
            int t = s[i1];
            s[i1] = s[i2];
            s[i2] += t;
        }
        __syncthreads();
    }
    int off = partial[b];
    if (g0 < n) out[g0] = s[tid] + off;
    if (g1 < n) out[g1] = s[tid + 256] + off;
}

__global__ void set_tail(int* __restrict__ row_ptr)
{
    row_ptr[NN] = ETOT;
}

// ================= counting sort of edges by dst-group =================
__global__ __launch_bounds__(256) void sort_hist(
    const int* __restrict__ ei, int* __restrict__ hist_bm, int* __restrict__ cnt)
{
    __shared__ int h[NBUCK];
    int tid = threadIdx.x, blk = blockIdx.x;
    h[tid] = 0;
    __syncthreads();
#pragma unroll
    for (int it = 0; it < EPB / 256; ++it) {
        int e = blk * EPB + it * 256 + tid;
        if (e < ETOT) {
            int d = edge_dst(ei, e);
            atomicAdd(&h[d >> 9], 1);
            atomicAdd(&cnt[d], 1);
        }
    }
    __syncthreads();
    hist_bm[tid * NBLK2 + blk] = h[tid];
}

__global__ __launch_bounds__(256) void sort_scatter(
    const int* __restrict__ ei, const int* __restrict__ off_bm, int2* __restrict__ srec)
{
    __shared__ int cur[NBUCK];
    int tid = threadIdx.x, blk = blockIdx.x;
    cur[tid] = off_bm[tid * NBLK2 + blk];
    __syncthreads();
#pragma unroll
    for (int it = 0; it < EPB / 256; ++it) {
        int e = blk * EPB + it * 256 + tid;
        if (e < ETOT) {
            int d = edge_dst(ei, e);
            int s = edge_src(ei, e);
            int pos = atomicAdd(&cur[d >> 9], 1);
            srec[pos] = make_int2(s, d);
        }
    }
}

__global__ __launch_bounds__(256) void csr_fill2(
    const int* __restrict__ row_ptr, const int2* __restrict__ srec, int* __restrict__ col_src)
{
    __shared__ int cur[512];
    int g = blockIdx.x, tid = threadIdx.x;
    int n0 = g << 9;
    for (int i = tid; i < 512; i += 256) {
        int nd = n0 + i;
        cur[i] = (nd < NN) ? row_ptr[nd] : 0;
    }
    __syncthreads();
    int lo = row_ptr[n0];
    int hi = (n0 + 512 <= NN) ? row_ptr[n0 + 512] : ETOT;
    for (int idx = lo + tid; idx < hi; idx += 256) {
        int2 r = srec[idx];
        int pos = atomicAdd(&cur[r.y - n0], 1);
        col_src[pos] = r.x;
    }
}

// ================= per-layer weight precomputes (att_vec + permW fused) =================
__global__ __launch_bounds__(256) void prep_kernel(
    const float* __restrict__ W, const float* __restrict__ attS,
    const float* __restrict__ attD, float* __restrict__ vs, float* __restrict__ vd,
    float* __restrict__ B2)
{
    int tid = threadIdx.x;
    if (blockIdx.x == 64) {
        int k = tid >> 2, h = tid & 3;
        const float* wr = W + (size_t)k * 256 + h * 64;
        const float* as = attS + h * 64;
        const float* ad = attD + h * 64;
        float ss = 0.f, sd = 0.f;
#pragma unroll
        for (int j = 0; j < 64; ++j) {
            float wv = wr[j];
            ss += wv * as[j];
            sd += wv * ad[j];
        }
        vs[tid] = ss;
        vd[tid] = sd;
    } else {
        int i = blockIdx.x * 256 + tid;   // i = r*64+j, r = h*64+k
        int r = i >> 6, j = i & 63;
        int h = r >> 6, k = r & 63;
        B2[i] = W[(size_t)k * 256 + h * 64 + j];
    }
}

// ================= attention scores directly from x =================
__global__ __launch_bounds__(256) void scores_x_kernel(
    const float* __restrict__ x, const float* __restrict__ vs,
    const float* __restrict__ vd, float4* __restrict__ a4s, float4* __restrict__ a4d)
{
    __shared__ float4 svs[64], svd[64];
    int tid = threadIdx.x;
    if (tid < 64) {
        svs[tid] = ((const float4*)vs)[tid];
        svd[tid] = ((const float4*)vd)[tid];
    }
    __syncthreads();
    int n = blockIdx.x * 256 + tid;
    if (n >= NN) return;
    const float4* xp = (const float4*)(x + (size_t)n * 64);
    float4 as = {0.f, 0.f, 0.f, 0.f}, ad = {0.f, 0.f, 0.f, 0.f};
#pragma unroll
    for (int i = 0; i < 16; ++i) {
        float4 xv = xp[i];
        float4 s0 = svs[i * 4 + 0], s1 = svs[i * 4 + 1], s2 = svs[i * 4 + 2], s3 = svs[i * 4 + 3];
        float4 d0 = svd[i * 4 + 0], d1 = svd[i * 4 + 1], d2 = svd[i * 4 + 2], d3 = svd[i * 4 + 3];
        as.x += xv.x * s0.x + xv.y * s1.x + xv.z * s2.x + xv.w * s3.x;
        as.y += xv.x * s0.y + xv.y * s1.y + xv.z * s2.y + xv.w * s3.y;
        as.z += xv.x * s0.z + xv.y * s1.z + xv.z * s2.z + xv.w * s3.z;
        as.w += xv.x * s0.w + xv.y * s1.w + xv.z * s2.w + xv.w * s3.w;
        ad.x += xv.x * d0.x + xv.y * d1.x + xv.z * d2.x + xv.w * d3.x;
        ad.y += xv.x * d0.y + xv.y * d1.y + xv.z * d2.y + xv.w * d3.y;
        ad.z += xv.x * d0.z + xv.y * d1.z + xv.z * d2.z + xv.w * d3.z;
        ad.w += xv.x * d0.w + xv.y * d1.w + xv.z * d2.w + xv.w * d3.w;
    }
    a4s[n] = as;
    a4d[n] = ad;
}

// ================= fused softmax + gather aggregation (wave per dst) =================
__global__ __launch_bounds__(256) void gat_fused(
    const int* __restrict__ row_ptr, const int* __restrict__ col_src,
    const float4* __restrict__ a4s, const float4* __restrict__ a4d,
    const float* __restrict__ x, float* __restrict__ agg)
{
    __shared__ float4 sp[4][CAP];
    __shared__ int    ssrc[4][CAP];
    const int wslot = threadIdx.x >> 6;
    const int lane = threadIdx.x & 63;
    const int d = (blockIdx.x * 256 + threadIdx.x) >> 6;   // grid sized so d < NN always

    const int rs = row_ptr[d];
    const int deg = row_ptr[d + 1] - rs;
    const float4 ad = a4d[d];

    // ---- Phase A: edge-parallel p + head sums ----
    float px = 0.f, py = 0.f, pz = 0.f, pw = 0.f;
    for (int base = 0; base < deg; base += 64) {
        int idx = base + lane;
        float4 p = {0.f, 0.f, 0.f, 0.f};
        int s = 0;
        if (idx < deg) {
            s = col_src[rs + idx];
            float4 v = a4s[s];
            p.x = fexp(lrelu(v.x + ad.x));
            p.y = fexp(lrelu(v.y + ad.y));
            p.z = fexp(lrelu(v.z + ad.z));
            p.w = fexp(lrelu(v.w + ad.w));
        }
        if (idx < CAP) { sp[wslot][idx] = p; ssrc[wslot][idx] = s; }
        px += p.x; py += p.y; pz += p.z; pw += p.w;
    }
#pragma unroll
    for (int off = 32; off > 0; off >>= 1) {
        px += __shfl_xor(px, off, 64);
        py += __shfl_xor(py, off, 64);
        pz += __shfl_xor(pz, off, 64);
        pw += __shfl_xor(pw, off, 64);
    }
    const float ivx = 0.25f * __builtin_amdgcn_rcpf(px);
    const float ivy = 0.25f * __builtin_amdgcn_rcpf(py);
    const float ivz = 0.25f * __builtin_amdgcn_rcpf(pz);
    const float ivw = 0.25f * __builtin_amdgcn_rcpf(pw);

    // ---- Phase B: feature-parallel x gather (scalar, 4-deep) ----
    float a0 = 0.f, a1 = 0.f, a2 = 0.f, a3 = 0.f;
    const int lim = deg < CAP ? deg : CAP;
    int e = 0;
    for (; e + 4 <= lim; e += 4) {
        float4 p0 = sp[wslot][e + 0], p1 = sp[wslot][e + 1];
        float4 p2 = sp[wslot][e + 2], p3 = sp[wslot][e + 3];
        int s0 = ssrc[wslot][e + 0], s1 = ssrc[wslot][e + 1];
        int s2 = ssrc[wslot][e + 2], s3 = ssrc[wslot][e + 3];
        float x0 = x[(size_t)s0 * 64 + lane];
        float x1 = x[(size_t)s1 * 64 + lane];
        float x2 = x[(size_t)s2 * 64 + lane];
        float x3 = x[(size_t)s3 * 64 + lane];
        a0 += p0.x * x0 + p1.x * x1 + p2.x * x2 + p3.x * x3;
        a1 += p0.y * x0 + p1.y * x1 + p2.y * x2 + p3.y * x3;
        a2 += p0.z * x0 + p1.z * x1 + p2.z * x2 + p3.z * x3;
        a3 += p0.w * x0 + p1.w * x1 + p2.w * x2 + p3.w * x3;
    }
    for (; e < lim; ++e) {
        float4 p = sp[wslot][e];
        int s = ssrc[wslot][e];
        float xv = x[(size_t)s * 64 + lane];
        a0 = fmaf(p.x, xv, a0);
        a1 = fmaf(p.y, xv, a1);
        a2 = fmaf(p.z, xv, a2);
        a3 = fmaf(p.w, xv, a3);
    }
    for (; e < deg; ++e) {   // slow path, statistically never taken
        int s = col_src[rs + e];
        float4 v = a4s[s];
        float4 p;
        p.x = fexp(lrelu(v.x + ad.x)); p.y = fexp(lrelu(v.y + ad.y));
        p.z = fexp(lrelu(v.z + ad.z)); p.w = fexp(lrelu(v.w + ad.w));
        float xv = x[(size_t)s * 64 + lane];
        a0 = fmaf(p.x, xv, a0);
        a1 = fmaf(p.y, xv, a1);
        a2 = fmaf(p.z, xv, a2);
        a3 = fmaf(p.w, xv, a3);
    }

    float* op = agg + (size_t)d * 256;
    __builtin_nontemporal_store(a0 * ivx, &op[lane]);
    __builtin_nontemporal_store(a1 * ivy, &op[64 + lane]);
    __builtin_nontemporal_store(a2 * ivz, &op[128 + lane]);
    __builtin_nontemporal_store(a3 * ivw, &op[192 + lane]);
}

// ---------------- host-side GAT layer ----------------
static void gat_layer(float* x /* in/out [N,64] */, const float* W, const float* attS,
                      const float* attD, const float* b, const int* row_ptr, const int* col_src,
                      float* agg, float4* a4s, float4* a4d,
                      float* vs, float* vd, float* B2, hipStream_t stream)
{
    prep_kernel<<<65, 256, 0, stream>>>(W, attS, attD, vs, vd, B2);
    scores_x_kernel<<<(NN + 255) / 256, 256, 0, stream>>>(x, vs, vd, a4s, a4d);
    gat_fused<<<(NN * 64) / 256, 256, 0, stream>>>(row_ptr, col_src, a4s, a4d, x, agg);
    // x_out = relu(agg @ B2 + b)   (0.25 folded into iv)
    gemm_kernel<<<(NN + 63) / 64, 256, 0, stream>>>(agg, B2, b, x, NN, 256, 64, 1);
}

extern "C" void kernel_launch(void* const* d_in, const int* in_sizes, int n_in,
                              void* d_out, int out_size, void* d_ws, size_t ws_size,
                              hipStream_t stream)
{
    const float* obs     = (const float*)d_in[0];
    const int*   ei      = (const int*)d_in[1];
    const float* enc_w1  = (const float*)d_in[2];
    const float* enc_b1  = (const float*)d_in[3];
    const float* enc_w2  = (const float*)d_in[4];
    const float* enc_b2  = (const float*)d_in[5];
    const float* gat1_w  = (const float*)d_in[6];
    const float* gat1_as = (const float*)d_in[7];
    const float* gat1_ad = (const float*)d_in[8];
    const float* gat1_b  = (const float*)d_in[9];
    const float* gat2_w  = (const float*)d_in[10];
    const float* gat2_as = (const float*)d_in[11];
    const float* gat2_ad = (const float*)d_in[12];
    const float* gat2_b  = (const float*)d_in[13];
    const float* dec_w1  = (const float*)d_in[14];
    const float* dec_b1  = (const float*)d_in[15];
    const float* dec_w2  = (const float*)d_in[16];
    const float* dec_b2  = (const float*)d_in[17];

    float* ws = (float*)d_ws;
    float* bufA    = ws;                                   // [N,64]
    float* bufB    = bufA + (size_t)NN * 64;               // [N,64]  (x)
    float* agg     = bufB + (size_t)NN * 64;               // [N,256]
    float4* a4s    = (float4*)(agg + (size_t)NN * 256);    // [N]
    float4* a4d    = a4s + NN;                             // [N]
    int* row_ptr   = (int*)(a4d + NN);                     // [N+1] (+pad)
    int* cnt       = row_ptr + NN + 4;                     // [N]
    int* col_src   = cnt + NN;                             // [ETOT]
    int* partial   = col_src + ETOT;                       // [256]
    int* partial2  = partial + 256;                        // [256]
    float* vs      = (float*)(partial2 + 256);             // [256]
    float* vd      = vs + 256;                             // [256]
    float* B2      = vd + 256;                             // [256*64]
    int* hist      = (int*)(B2 + 256 * 64);                // [NSCAN]
    int* off_bm    = hist + NSCAN;                         // [NSCAN]
    int2* srec     = (int2*)(off_bm + NSCAN);              // [ETOT]

    const int GB = (NN + 63) / 64;
    const int NCHUNK_N = (NN + 511) / 512;        // 196
    const int NCHUNK_S = (NSCAN + 511) / 512;     // 220

    // ---- CSR build via counting sort (once, reused by both GAT layers) ----
    hipMemsetAsync(cnt, 0, (size_t)NN * sizeof(int), stream);
    sort_hist<<<NBLK2, 256, 0, stream>>>(ei, hist, cnt);
    gscan_partial<<<NCHUNK_N, 256, 0, stream>>>(cnt, partial, NN);
    gscan_top<<<1, 256, 0, stream>>>(partial, NCHUNK_N);
    gscan_final<<<NCHUNK_N, 256, 0, stream>>>(cnt, partial, row_ptr, NN);
    set_tail<<<1, 1, 0, stream>>>(row_ptr);
    gscan_partial<<<NCHUNK_S, 256, 0, stream>>>(hist, partial2, NSCAN);
    gscan_top<<<1, 256, 0, stream>>>(partial2, NCHUNK_S);
    gscan_final<<<NCHUNK_S, 256, 0, stream>>>(hist, partial2, off_bm, NSCAN);
    sort_scatter<<<NBLK2, 256, 0, stream>>>(ei, off_bm, srec);
    csr_fill2<<<NGRP, 256, 0, stream>>>(row_ptr, srec, col_src);

    // ---- encoder ----
    gemm_kernel<<<GB, 256, 0, stream>>>(obs, enc_w1, enc_b1, bufA, NN, 128, 64, 1);
    gemm_kernel<<<GB, 256, 0, stream>>>(bufA, enc_w2, enc_b2, bufB, NN, 64, 64, 0);

    // ---- GAT layers (x lives in bufB) ----
    gat_layer(bufB, gat1_w, gat1_as, gat1_ad, gat1_b, row_ptr, col_src, agg, a4s, a4d, vs, vd, B2, stream);
    gat_layer(bufB, gat2_w, gat2_as, gat2_ad, gat2_b, row_ptr, col_src, agg, a4s, a4d, vs, vd, B2, stream);

    // ---- decoder ----
    gemm_kernel<<<GB, 256, 0, stream>>>(bufB, dec_w1, dec_b1, bufA, NN, 64, 64, 1);
    gemm_kernel<<<GB, 256, 0, stream>>>(bufA, dec_w2, dec_b2, (float*)d_out, NN, 64, 32, 0);
}